// Round 1
// baseline (457.345 us; speedup 1.0000x reference)
//
#include <hip/hip_runtime.h>

// CGConv x2 + masked linear readout for N=50000, E=800000, C=64.
// Strategy: bf16 MFMA edge-GEMM ([64 edges][128] x [128][128] per tile),
// fp32 atomicAdd aggregation, fp32 residual/readout.
// ws layout: agg(12.8MB) | scal(64B) | h1(12.8MB) | xb(6.4MB) | h1b(6.4MB) | wt(64KB)

#define NN 50000
#define EE 800000
#define NTILES (EE / 64)

typedef short bf16x8 __attribute__((ext_vector_type(8)));
typedef float f32x4 __attribute__((ext_vector_type(4)));
typedef unsigned int uint4v __attribute__((ext_vector_type(4)));
typedef unsigned short u16x4 __attribute__((ext_vector_type(4)));

__device__ __forceinline__ unsigned short f2b(float f) {
    unsigned int u = __builtin_bit_cast(unsigned int, f);
    return (unsigned short)((u + 0x7fffu + ((u >> 16) & 1u)) >> 16);
}

// fp32 -> bf16 copy of node features
__global__ __launch_bounds__(256) void k_prep_x(const float* __restrict__ x,
                                                unsigned short* __restrict__ xb) {
    int i = (blockIdx.x * 256 + threadIdx.x) * 4;  // 3.2M elems / 4 = 800k threads
    f32x4 v = *(const f32x4*)(x + i);
    u16x4 o;
    o[0] = f2b(v[0]); o[1] = f2b(v[1]); o[2] = f2b(v[2]); o[3] = f2b(v[3]);
    *(u16x4*)(xb + i) = o;
}

// Build Wt[layer][n][k] bf16 (n<64: Wf[k][n], else Ws[k][n-64]), pre-XOR-swizzled
// so a linear 32KB copy into LDS yields the swizzled read layout.
__global__ __launch_bounds__(256) void k_prep_w(const float* __restrict__ Wf1, const float* __restrict__ Ws1,
                                                const float* __restrict__ Wf2, const float* __restrict__ Ws2,
                                                unsigned short* __restrict__ wt) {
    int i = blockIdx.x * 256 + threadIdx.x;  // 0..32767
    int layer = i >> 14;
    int j = i & 16383;
    int n = j >> 7, k = j & 127;
    const float* Wf = layer ? Wf2 : Wf1;
    const float* Ws = layer ? Ws2 : Ws1;
    float v = (n < 64) ? Wf[k * 64 + n] : Ws[k * 64 + (n - 64)];
    int byte = ((n * 256 + k * 2) ^ ((n & 7) << 4)) + layer * 32768;
    *(unsigned short*)((char*)wt + byte) = f2b(v);
}

// One edge-tile = 64 edges. Block: 256 thr (4 waves), each wave 16 edges x 128 outs.
// F = z@Wf+bf (cols 0..63), S = z@Ws+bs (cols 64..127); msg = sigmoid(F)*softplus(S).
__global__ __launch_bounds__(256) void k_edge(const unsigned short* __restrict__ hb,
                                              const int* __restrict__ ei,
                                              const unsigned short* __restrict__ wt,
                                              const float* __restrict__ bfv,
                                              const float* __restrict__ bsv,
                                              float* __restrict__ agg) {
    __shared__ unsigned short wt_s[128 * 128];  // 32KB, swizzled
    __shared__ unsigned short z_s[64 * 128];    // 16KB, swizzled
    __shared__ int dst_s[64];

    const int t = threadIdx.x;
    {   // W: one coalesced 32KB copy (already swizzled in global)
        const uint4v* src = (const uint4v*)wt;
        uint4v* dp = (uint4v*)wt_s;
        #pragma unroll
        for (int i = 0; i < 8; ++i) dp[t + 256 * i] = src[t + 256 * i];
    }
    const int lane = t & 63;
    const int wid = t >> 6;
    const int cbase = lane & 15;
    const int q = lane >> 4;
    float bF[4], bS[4];
    #pragma unroll
    for (int nf = 0; nf < 4; ++nf) { bF[nf] = bfv[nf * 16 + cbase]; bS[nf] = bsv[nf * 16 + cbase]; }

    for (int tile = blockIdx.x; tile < NTILES; tile += gridDim.x) {
        __syncthreads();  // z_s reuse guard (also covers first-iter W load)
        // gather: 64 rows x 16 chunks(16B); cols 0..63 = x[dst], 64..127 = x[src]
        #pragma unroll
        for (int i = 0; i < 4; ++i) {
            int chunk = t + 256 * i;
            int r = chunk >> 4;
            int c16 = chunk & 15;
            int e = tile * 64 + r;
            int node = (c16 < 8) ? ei[EE + e] : ei[e];  // dst half first (x_i = target)
            uint4v v = *(const uint4v*)(hb + node * 64 + (c16 & 7) * 8);
            int byte = (r * 256 + c16 * 16) ^ ((r & 7) << 4);
            *(uint4v*)((char*)z_s + byte) = v;
            if (c16 == 0) dst_s[r] = node;
        }
        __syncthreads();

        f32x4 acc[8];
        #pragma unroll
        for (int nf = 0; nf < 8; ++nf) acc[nf] = (f32x4){0.f, 0.f, 0.f, 0.f};

        const int mr = wid * 16 + cbase;       // A row (edge within tile)
        const int aswz = (mr & 7) << 4;
        #pragma unroll
        for (int ks = 0; ks < 4; ++ks) {
            bf16x8 a = *(const bf16x8*)((const char*)z_s + mr * 256 + ((ks * 64 + q * 16) ^ aswz));
            #pragma unroll
            for (int nf = 0; nf < 8; ++nf) {
                int bn = nf * 16 + cbase;
                bf16x8 b = *(const bf16x8*)((const char*)wt_s + bn * 256 + ((ks * 64 + q * 16) ^ ((bn & 7) << 4)));
                acc[nf] = __builtin_amdgcn_mfma_f32_16x16x32_bf16(a, b, acc[nf], 0, 0, 0);
            }
        }

        // epilogue: C/D layout col=lane&15, row=(lane>>4)*4+r
        #pragma unroll
        for (int r = 0; r < 4; ++r) {
            int row = wid * 16 + q * 4 + r;
            int dst = dst_s[row];
            #pragma unroll
            for (int nf = 0; nf < 4; ++nf) {
                float F = acc[nf][r] + bF[nf];
                float S = acc[nf + 4][r] + bS[nf];
                float sig = 1.f / (1.f + __expf(-F));
                float sp = (S > 20.f) ? S : __logf(1.f + __expf(S));
                atomicAdd(agg + dst * 64 + nf * 16 + cbase, sig * sp);
            }
        }
    }
}

// h1 = x + agg; also bf16 copy; re-zero agg for layer 2
__global__ __launch_bounds__(256) void k_residual(const float* __restrict__ x, float* __restrict__ agg,
                                                  float* __restrict__ h1, unsigned short* __restrict__ h1b) {
    int i = (blockIdx.x * 256 + threadIdx.x) * 4;
    f32x4 xv = *(const f32x4*)(x + i);
    f32x4 av = *(const f32x4*)(agg + i);
    f32x4 h; u16x4 hb;
    #pragma unroll
    for (int j = 0; j < 4; ++j) { h[j] = xv[j] + av[j]; hb[j] = f2b(h[j]); }
    *(f32x4*)(h1 + i) = h;
    *(u16x4*)(h1b + i) = hb;
    *(f32x4*)(agg + i) = (f32x4){0.f, 0.f, 0.f, 0.f};
}

// y numerator/denominator partial sums. h2 = h1 + agg2; o = (h2 . Wlin); so += surf*o; ss += surf
__global__ __launch_bounds__(256) void k_reduce(const float* __restrict__ h1, const float* __restrict__ agg,
                                                const float* __restrict__ surf, const float* __restrict__ Wlin,
                                                float* __restrict__ scal) {
    const int lane = threadIdx.x & 63;
    const int wid = threadIdx.x >> 6;
    float w = Wlin[lane];
    float so = 0.f, ss = 0.f;
    for (int n = blockIdx.x * 4 + wid; n < NN; n += gridDim.x * 4) {
        float v = (h1[n * 64 + lane] + agg[n * 64 + lane]) * w;
        #pragma unroll
        for (int off = 32; off; off >>= 1) v += __shfl_xor(v, off);
        if (lane == 0) { so += v * surf[n]; ss += surf[n]; }
    }
    __shared__ float ps[8];
    if (lane == 0) { ps[wid] = so; ps[4 + wid] = ss; }
    __syncthreads();
    if (threadIdx.x == 0) {
        atomicAdd(scal + 0, ps[0] + ps[1] + ps[2] + ps[3]);
        atomicAdd(scal + 1, ps[4] + ps[5] + ps[6] + ps[7]);
    }
}

__global__ void k_final(const float* __restrict__ scal, const float* __restrict__ blin,
                        float* __restrict__ out) {
    out[0] = (scal[0] + (float)NN * blin[0]) / scal[1];
}

extern "C" void kernel_launch(void* const* d_in, const int* in_sizes, int n_in,
                              void* d_out, int out_size, void* d_ws, size_t ws_size,
                              hipStream_t stream) {
    const float* x    = (const float*)d_in[0];
    const int*   ei   = (const int*)d_in[1];
    const float* surf = (const float*)d_in[2];
    const float* Wf1  = (const float*)d_in[3];
    const float* bf1  = (const float*)d_in[4];
    const float* Ws1  = (const float*)d_in[5];
    const float* bs1  = (const float*)d_in[6];
    const float* Wf2  = (const float*)d_in[7];
    const float* bf2  = (const float*)d_in[8];
    const float* Ws2  = (const float*)d_in[9];
    const float* bs2  = (const float*)d_in[10];
    const float* Wlin = (const float*)d_in[11];
    const float* blin = (const float*)d_in[12];

    unsigned char* ws = (unsigned char*)d_ws;
    float* agg  = (float*)(ws);                              // 12,800,000 B
    float* scal = (float*)(ws + 12800000);                   // 64 B
    float* h1   = (float*)(ws + 12800064);                   // 12,800,000 B
    unsigned short* xb  = (unsigned short*)(ws + 25600064);  // 6,400,000 B
    unsigned short* h1b = (unsigned short*)(ws + 32000064);  // 6,400,000 B
    unsigned short* wt  = (unsigned short*)(ws + 38400064);  // 65,536 B

    hipMemsetAsync(d_ws, 0, 12800064, stream);  // agg + scal
    k_prep_x<<<3125, 256, 0, stream>>>(x, xb);
    k_prep_w<<<128, 256, 0, stream>>>(Wf1, Ws1, Wf2, Ws2, wt);
    k_edge<<<2048, 256, 0, stream>>>(xb, ei, wt, bf1, bs1, agg);
    k_residual<<<3125, 256, 0, stream>>>(x, agg, h1, h1b);
    k_edge<<<2048, 256, 0, stream>>>(h1b, ei, wt + 16384, bf2, bs2, agg);
    k_reduce<<<512, 256, 0, stream>>>(h1, agg, surf, Wlin, scal);
    k_final<<<1, 1, 0, stream>>>(scal, blin, (float*)d_out);
}

// Round 2
// 409.892 us; speedup vs baseline: 1.1158x; 1.1158x over previous
//
#include <hip/hip_runtime.h>

// CGConv x2 + masked readout. N=50000, E=800000, C=64.
// Restructure: per-node projections (MFMA GEMM N x 64 @ 64 x 256) + CSR gather
// (wave-per-node, register accumulation) -- no fp32 atomics, no edge GEMM.
//
// ws layout (35.9 MB total):
//  deg(200704) csum(256) scal(64) start(200704) cursor(200704) esrc(3.2M)
//  h1b(6.4M) Pd(12.8M) Ps(12.8M) wt(64K)

#define NN 50000
#define EE 800000
#define N2 50176          // 49*1024, padded for scan
#define NTILE 782         // ceil(50000/64)

typedef short bf16x8 __attribute__((ext_vector_type(8)));
typedef float f32x4 __attribute__((ext_vector_type(4)));
typedef unsigned int uint4v __attribute__((ext_vector_type(4)));
typedef unsigned short u16x4 __attribute__((ext_vector_type(4)));

__device__ __forceinline__ unsigned short f2b(float f) {
    unsigned int u = __builtin_bit_cast(unsigned int, f);
    return (unsigned short)((u + 0x7fffu + ((u >> 16) & 1u)) >> 16);
}
__device__ __forceinline__ float b2f(unsigned short b) {
    unsigned int u = ((unsigned int)b) << 16;
    return __builtin_bit_cast(float, u);
}
__device__ __forceinline__ float sigsp(float F, float S) {
    float sig = 1.f / (1.f + __expf(-F));
    float sp = (S > 20.f) ? S : __logf(1.f + __expf(S));
    return sig * sp;
}

// Pack both layers' weights: wt[layer][n][k] bf16 where n=output col (0..255),
// k=input chan (0..63). Cols: [0,64)=Wf_top, [64,128)=Ws_top, [128,192)=Wf_bot,
// [192,256)=Ws_bot. Pre-XOR-swizzled so a linear LDS copy gives swizzled layout.
__global__ __launch_bounds__(256) void k_prep_w(const float* __restrict__ Wf1, const float* __restrict__ Ws1,
                                                const float* __restrict__ Wf2, const float* __restrict__ Ws2,
                                                unsigned short* __restrict__ wt) {
    int i = blockIdx.x * 256 + threadIdx.x;   // 0..32767
    int layer = i >> 14;
    int j = i & 16383;
    int n = j >> 6, k = j & 63;
    const float* Wf = layer ? Wf2 : Wf1;
    const float* Ws = layer ? Ws2 : Ws1;
    float v;
    if (n < 64)       v = Wf[k * 64 + n];
    else if (n < 128) v = Ws[k * 64 + (n - 64)];
    else if (n < 192) v = Wf[(64 + k) * 64 + (n - 128)];
    else              v = Ws[(64 + k) * 64 + (n - 192)];
    int byte = ((n * 128 + k * 2) ^ ((n & 7) << 4)) + layer * 32768;
    *(unsigned short*)((char*)wt + byte) = f2b(v);
}

__global__ __launch_bounds__(256) void k_deg(const int* __restrict__ ei, int* __restrict__ deg) {
    int e = blockIdx.x * 256 + threadIdx.x;
    atomicAdd(&deg[ei[EE + e]], 1);
}

__global__ __launch_bounds__(1024) void k_scan1(const int* __restrict__ deg, int* __restrict__ start,
                                                int* __restrict__ csum) {
    __shared__ int s[1024];
    int t = threadIdx.x;
    int i = blockIdx.x * 1024 + t;
    int v = deg[i];
    s[t] = v; __syncthreads();
    for (int off = 1; off < 1024; off <<= 1) {
        int y = (t >= off) ? s[t - off] : 0; __syncthreads();
        s[t] += y; __syncthreads();
    }
    start[i] = s[t] - v;
    if (t == 1023) csum[blockIdx.x] = s[t];
}

__global__ void k_scan2(int* __restrict__ csum) {
    __shared__ int s[64];
    int t = threadIdx.x;
    int v = (t < 49) ? csum[t] : 0;
    s[t] = v; __syncthreads();
    for (int off = 1; off < 64; off <<= 1) {
        int y = (t >= off) ? s[t - off] : 0; __syncthreads();
        s[t] += y; __syncthreads();
    }
    if (t < 49) csum[t] = s[t] - v;
}

__global__ __launch_bounds__(1024) void k_scan3(int* __restrict__ start, const int* __restrict__ csum,
                                                int* __restrict__ cursor) {
    int i = blockIdx.x * 1024 + threadIdx.x;
    int v = start[i] + csum[blockIdx.x];
    start[i] = v;
    cursor[i] = v;
}

__global__ __launch_bounds__(256) void k_fill(const int* __restrict__ ei, int* __restrict__ cursor,
                                              int* __restrict__ esrc) {
    int e = blockIdx.x * 256 + threadIdx.x;
    int dst = ei[EE + e];
    int p = atomicAdd(&cursor[dst], 1);
    esrc[p] = ei[e];
}

// P = H @ Wcat. Block: 64 nodes x 256 cols, 4 waves (each 64x64 quadrant group).
// Pd[n][0:128] = [F_dst | S_dst], Ps[n][0:128] = [F_src+bf | S_src+bs].
template <bool F32IN>
__global__ __launch_bounds__(256) void k_proj(const void* __restrict__ hin,
                                              const unsigned short* __restrict__ wt,
                                              const float* __restrict__ bfv, const float* __restrict__ bsv,
                                              unsigned short* __restrict__ Pd, unsigned short* __restrict__ Ps) {
    __shared__ unsigned short w_s[256 * 64];  // 32KB swizzled
    __shared__ unsigned short a_s[64 * 64];   // 8KB swizzled
    const int t = threadIdx.x;
    {
        const uint4v* src = (const uint4v*)wt;
        uint4v* dp = (uint4v*)w_s;
        #pragma unroll
        for (int i = 0; i < 8; ++i) dp[t + 256 * i] = src[t + 256 * i];
    }
    const int lane = t & 63, wid = t >> 6;
    const int cbase = lane & 15, q = lane >> 4;
    const int tile = blockIdx.x;

    #pragma unroll
    for (int i = 0; i < 2; ++i) {
        int ch = t + 256 * i;
        int r = ch >> 3, c8 = ch & 7;
        int node = tile * 64 + r;
        u16x4 lo = {0, 0, 0, 0}, hi = {0, 0, 0, 0};
        if (node < NN) {
            if (F32IN) {
                const float* xp = (const float*)hin + node * 64 + c8 * 8;
                f32x4 v0 = *(const f32x4*)xp;
                f32x4 v1 = *(const f32x4*)(xp + 4);
                lo[0] = f2b(v0[0]); lo[1] = f2b(v0[1]); lo[2] = f2b(v0[2]); lo[3] = f2b(v0[3]);
                hi[0] = f2b(v1[0]); hi[1] = f2b(v1[1]); hi[2] = f2b(v1[2]); hi[3] = f2b(v1[3]);
            } else {
                const unsigned short* hp = (const unsigned short*)hin + node * 64 + c8 * 8;
                lo = *(const u16x4*)hp;
                hi = *(const u16x4*)(hp + 4);
            }
        }
        int byte = (r * 128 + c8 * 16) ^ ((r & 7) << 4);
        *(u16x4*)((char*)a_s + byte) = lo;
        *(u16x4*)((char*)a_s + byte + 8) = hi;
    }
    __syncthreads();

    f32x4 acc[4][4];
    #pragma unroll
    for (int m = 0; m < 4; ++m)
        #pragma unroll
        for (int n = 0; n < 4; ++n) acc[m][n] = (f32x4){0.f, 0.f, 0.f, 0.f};

    #pragma unroll
    for (int ks = 0; ks < 2; ++ks) {
        bf16x8 a[4];
        #pragma unroll
        for (int m = 0; m < 4; ++m) {
            int mr = m * 16 + cbase;
            a[m] = *(const bf16x8*)((const char*)a_s + mr * 128 + ((ks * 64 + q * 16) ^ ((mr & 7) << 4)));
        }
        #pragma unroll
        for (int n = 0; n < 4; ++n) {
            int bn = wid * 64 + n * 16 + cbase;
            bf16x8 b = *(const bf16x8*)((const char*)w_s + bn * 128 + ((ks * 64 + q * 16) ^ ((bn & 7) << 4)));
            #pragma unroll
            for (int m = 0; m < 4; ++m)
                acc[m][n] = __builtin_amdgcn_mfma_f32_16x16x32_bf16(a[m], b, acc[m][n], 0, 0, 0);
        }
    }

    #pragma unroll
    for (int n = 0; n < 4; ++n) {
        int col = wid * 64 + n * 16 + cbase;
        float bias = 0.f;
        if (col >= 192) bias = bsv[col - 192];
        else if (col >= 128) bias = bfv[col - 128];
        unsigned short* outp = (col < 128) ? Pd : Ps;
        int ocol = col & 127;
        #pragma unroll
        for (int m = 0; m < 4; ++m) {
            int node = tile * 64 + m * 16 + q * 4;
            #pragma unroll
            for (int r = 0; r < 4; ++r)
                outp[(node + r) * 128 + ocol] = f2b(acc[m][n][r] + bias);
        }
    }
}

// Wave per node: gather incoming edges via CSR, accumulate msg in registers.
// LAYER 1: h1b = bf16(x + agg). LAYER 2: fused residual + surf mask + Wlin dot + reduce.
template <int LAYER>
__global__ __launch_bounds__(256) void k_gather(const unsigned short* __restrict__ Pd,
                                                const unsigned short* __restrict__ Ps,
                                                const int* __restrict__ esrc, const int* __restrict__ start,
                                                const int* __restrict__ deg, const float* __restrict__ x,
                                                unsigned short* __restrict__ h1b,
                                                const float* __restrict__ surf, const float* __restrict__ Wlin,
                                                float* __restrict__ scal) {
    const int lane = threadIdx.x & 63, wid = threadIdx.x >> 6;
    const int gw = blockIdx.x * 4 + wid, nw = gridDim.x * 4;
    float wlin = (LAYER == 2) ? Wlin[lane] : 0.f;
    float so = 0.f, ssum = 0.f;

    for (int n = gw; n < NN; n += nw) {
        float fd = b2f(Pd[n * 128 + lane]);
        float sd = b2f(Pd[n * 128 + 64 + lane]);
        int b = start[n], d = deg[n];
        float acc0 = 0.f, acc1 = 0.f;
        for (int j = 0; j < d; j += 2) {
            int s0 = esrc[b + j];
            float F0 = fd + b2f(Ps[s0 * 128 + lane]);
            float S0 = sd + b2f(Ps[s0 * 128 + 64 + lane]);
            acc0 += sigsp(F0, S0);
            if (j + 1 < d) {
                int s1 = esrc[b + j + 1];
                float F1 = fd + b2f(Ps[s1 * 128 + lane]);
                float S1 = sd + b2f(Ps[s1 * 128 + 64 + lane]);
                acc1 += sigsp(F1, S1);
            }
        }
        float agg = acc0 + acc1;
        if (LAYER == 1) {
            h1b[n * 64 + lane] = f2b(x[n * 64 + lane] + agg);
        } else {
            float v = (b2f(h1b[n * 64 + lane]) + agg) * wlin;
            #pragma unroll
            for (int off = 32; off; off >>= 1) v += __shfl_xor(v, off);
            if (lane == 0) { so += v * surf[n]; ssum += surf[n]; }
        }
    }
    if (LAYER == 2) {
        __shared__ float ps[8];
        if (lane == 0) { ps[wid] = so; ps[4 + wid] = ssum; }
        __syncthreads();
        if (threadIdx.x == 0) {
            atomicAdd(scal + 0, ps[0] + ps[1] + ps[2] + ps[3]);
            atomicAdd(scal + 1, ps[4] + ps[5] + ps[6] + ps[7]);
        }
    }
}

__global__ void k_final(const float* __restrict__ scal, const float* __restrict__ blin,
                        float* __restrict__ out) {
    out[0] = (scal[0] + (float)NN * blin[0]) / scal[1];
}

extern "C" void kernel_launch(void* const* d_in, const int* in_sizes, int n_in,
                              void* d_out, int out_size, void* d_ws, size_t ws_size,
                              hipStream_t stream) {
    const float* x    = (const float*)d_in[0];
    const int*   ei   = (const int*)d_in[1];
    const float* surf = (const float*)d_in[2];
    const float* Wf1  = (const float*)d_in[3];
    const float* bf1  = (const float*)d_in[4];
    const float* Ws1  = (const float*)d_in[5];
    const float* bs1  = (const float*)d_in[6];
    const float* Wf2  = (const float*)d_in[7];
    const float* bf2  = (const float*)d_in[8];
    const float* Ws2  = (const float*)d_in[9];
    const float* bs2  = (const float*)d_in[10];
    const float* Wlin = (const float*)d_in[11];
    const float* blin = (const float*)d_in[12];

    unsigned char* ws = (unsigned char*)d_ws;
    int* deg    = (int*)(ws);                      // 200704 B (N2 ints)
    int* csum   = (int*)(ws + 200704);             // 256 B
    float* scal = (float*)(ws + 200960);           // 64 B
    int* start  = (int*)(ws + 201024);             // 200704 B
    int* cursor = (int*)(ws + 401728);             // 200704 B
    int* esrc   = (int*)(ws + 602432);             // 3,200,000 B
    unsigned short* h1b = (unsigned short*)(ws + 3802432);   // 6,406,144 B (50048x64)
    unsigned short* Pd  = (unsigned short*)(ws + 10208576);  // 12,812,288 B (50048x128)
    unsigned short* Ps  = (unsigned short*)(ws + 23020864);  // 12,812,288 B
    unsigned short* wt  = (unsigned short*)(ws + 35833152);  // 65,536 B

    hipMemsetAsync(d_ws, 0, 201024, stream);  // deg + csum + scal

    k_prep_w<<<128, 256, 0, stream>>>(Wf1, Ws1, Wf2, Ws2, wt);
    k_deg<<<3125, 256, 0, stream>>>(ei, deg);
    k_scan1<<<49, 1024, 0, stream>>>(deg, start, csum);
    k_scan2<<<1, 64, 0, stream>>>(csum);
    k_scan3<<<49, 1024, 0, stream>>>(start, csum, cursor);
    k_fill<<<3125, 256, 0, stream>>>(ei, cursor, esrc);

    k_proj<true><<<NTILE, 256, 0, stream>>>(x, wt, bf1, bs1, Pd, Ps);
    k_gather<1><<<1024, 256, 0, stream>>>(Pd, Ps, esrc, start, deg, x, h1b, surf, Wlin, scal);
    k_proj<false><<<NTILE, 256, 0, stream>>>(h1b, wt + 16384, bf2, bs2, Pd, Ps);
    k_gather<2><<<1024, 256, 0, stream>>>(Pd, Ps, esrc, start, deg, x, h1b, surf, Wlin, scal);
    k_final<<<1, 1, 0, stream>>>(scal, blin, (float*)d_out);
}

// Round 3
// 302.552 us; speedup vs baseline: 1.5116x; 1.3548x over previous
//
#include <hip/hip_runtime.h>

// CGConv x2 + masked readout. N=50000, E=800000, C=64.
// Per-node projections (MFMA) + CSR gather (wave-per-node, register acc).
// R3: packed F/S dword loads in gather, lane-preloaded edge indices (+shfl),
// 4-deep unroll, 2048-block gather grid.
//
// ws layout: deg(200704) csum(256) scal(64) start(200704) cursor(200704)
// esrc(3.2M) h1b(6.4M) Pd(12.8M) Ps(12.8M) wt(64K)

#define NN 50000
#define EE 800000
#define N2 50176          // 49*1024, padded for scan
#define NTILE 782         // ceil(50000/64)

typedef short bf16x8 __attribute__((ext_vector_type(8)));
typedef float f32x4 __attribute__((ext_vector_type(4)));
typedef unsigned int uint4v __attribute__((ext_vector_type(4)));
typedef unsigned short u16x4 __attribute__((ext_vector_type(4)));

__device__ __forceinline__ unsigned short f2b(float f) {
    unsigned int u = __builtin_bit_cast(unsigned int, f);
    return (unsigned short)((u + 0x7fffu + ((u >> 16) & 1u)) >> 16);
}
__device__ __forceinline__ float b2f(unsigned short b) {
    unsigned int u = ((unsigned int)b) << 16;
    return __builtin_bit_cast(float, u);
}
__device__ __forceinline__ float lo16f(unsigned int v) {
    return __builtin_bit_cast(float, v << 16);
}
__device__ __forceinline__ float hi16f(unsigned int v) {
    return __builtin_bit_cast(float, v & 0xFFFF0000u);
}
__device__ __forceinline__ float sigsp(float F, float S) {
    float sig = 1.f / (1.f + __expf(-F));
    float sp = (S > 20.f) ? S : __logf(1.f + __expf(S));
    return sig * sp;
}

// wt[layer][n][k] bf16, n=out col 0..255 ([Wf_top|Ws_top|Wf_bot|Ws_bot]),
// k=in chan 0..63, pre-XOR-swizzled for linear LDS copy.
__global__ __launch_bounds__(256) void k_prep_w(const float* __restrict__ Wf1, const float* __restrict__ Ws1,
                                                const float* __restrict__ Wf2, const float* __restrict__ Ws2,
                                                unsigned short* __restrict__ wt) {
    int i = blockIdx.x * 256 + threadIdx.x;   // 0..32767
    int layer = i >> 14;
    int j = i & 16383;
    int n = j >> 6, k = j & 63;
    const float* Wf = layer ? Wf2 : Wf1;
    const float* Ws = layer ? Ws2 : Ws1;
    float v;
    if (n < 64)       v = Wf[k * 64 + n];
    else if (n < 128) v = Ws[k * 64 + (n - 64)];
    else if (n < 192) v = Wf[(64 + k) * 64 + (n - 128)];
    else              v = Ws[(64 + k) * 64 + (n - 192)];
    int byte = ((n * 128 + k * 2) ^ ((n & 7) << 4)) + layer * 32768;
    *(unsigned short*)((char*)wt + byte) = f2b(v);
}

__global__ __launch_bounds__(256) void k_deg(const int* __restrict__ ei, int* __restrict__ deg) {
    int e = blockIdx.x * 256 + threadIdx.x;
    atomicAdd(&deg[ei[EE + e]], 1);
}

__global__ __launch_bounds__(1024) void k_scan1(const int* __restrict__ deg, int* __restrict__ start,
                                                int* __restrict__ csum) {
    __shared__ int s[1024];
    int t = threadIdx.x;
    int i = blockIdx.x * 1024 + t;
    int v = deg[i];
    s[t] = v; __syncthreads();
    for (int off = 1; off < 1024; off <<= 1) {
        int y = (t >= off) ? s[t - off] : 0; __syncthreads();
        s[t] += y; __syncthreads();
    }
    start[i] = s[t] - v;
    if (t == 1023) csum[blockIdx.x] = s[t];
}

__global__ void k_scan2(int* __restrict__ csum) {
    __shared__ int s[64];
    int t = threadIdx.x;
    int v = (t < 49) ? csum[t] : 0;
    s[t] = v; __syncthreads();
    for (int off = 1; off < 64; off <<= 1) {
        int y = (t >= off) ? s[t - off] : 0; __syncthreads();
        s[t] += y; __syncthreads();
    }
    if (t < 49) csum[t] = s[t] - v;
}

__global__ __launch_bounds__(1024) void k_scan3(int* __restrict__ start, const int* __restrict__ csum,
                                                int* __restrict__ cursor) {
    int i = blockIdx.x * 1024 + threadIdx.x;
    int v = start[i] + csum[blockIdx.x];
    start[i] = v;
    cursor[i] = v;
}

__global__ __launch_bounds__(256) void k_fill(const int* __restrict__ ei, int* __restrict__ cursor,
                                              int* __restrict__ esrc) {
    int e = blockIdx.x * 256 + threadIdx.x;
    int dst = ei[EE + e];
    int p = atomicAdd(&cursor[dst], 1);
    esrc[p] = ei[e];
}

// P = H @ Wcat, 64 nodes x 256 cols per block, 4 waves.
// Output layout (per node, 64 dwords): dword c = [F_c (lo16) | S_c (hi16)].
// Pd: no bias. Ps: +bf/+bs folded in.
template <bool F32IN>
__global__ __launch_bounds__(256) void k_proj(const void* __restrict__ hin,
                                              const unsigned short* __restrict__ wt,
                                              const float* __restrict__ bfv, const float* __restrict__ bsv,
                                              unsigned short* __restrict__ Pd, unsigned short* __restrict__ Ps) {
    __shared__ unsigned short w_s[256 * 64];  // 32KB swizzled
    __shared__ unsigned short a_s[64 * 64];   // 8KB swizzled
    const int t = threadIdx.x;
    {
        const uint4v* src = (const uint4v*)wt;
        uint4v* dp = (uint4v*)w_s;
        #pragma unroll
        for (int i = 0; i < 8; ++i) dp[t + 256 * i] = src[t + 256 * i];
    }
    const int lane = t & 63, wid = t >> 6;
    const int cbase = lane & 15, q = lane >> 4;
    const int tile = blockIdx.x;

    #pragma unroll
    for (int i = 0; i < 2; ++i) {
        int ch = t + 256 * i;
        int r = ch >> 3, c8 = ch & 7;
        int node = tile * 64 + r;
        u16x4 lo = {0, 0, 0, 0}, hi = {0, 0, 0, 0};
        if (node < NN) {
            if (F32IN) {
                const float* xp = (const float*)hin + node * 64 + c8 * 8;
                f32x4 v0 = *(const f32x4*)xp;
                f32x4 v1 = *(const f32x4*)(xp + 4);
                lo[0] = f2b(v0[0]); lo[1] = f2b(v0[1]); lo[2] = f2b(v0[2]); lo[3] = f2b(v0[3]);
                hi[0] = f2b(v1[0]); hi[1] = f2b(v1[1]); hi[2] = f2b(v1[2]); hi[3] = f2b(v1[3]);
            } else {
                const unsigned short* hp = (const unsigned short*)hin + node * 64 + c8 * 8;
                lo = *(const u16x4*)hp;
                hi = *(const u16x4*)(hp + 4);
            }
        }
        int byte = (r * 128 + c8 * 16) ^ ((r & 7) << 4);
        *(u16x4*)((char*)a_s + byte) = lo;
        *(u16x4*)((char*)a_s + byte + 8) = hi;
    }
    __syncthreads();

    f32x4 acc[4][4];
    #pragma unroll
    for (int m = 0; m < 4; ++m)
        #pragma unroll
        for (int n = 0; n < 4; ++n) acc[m][n] = (f32x4){0.f, 0.f, 0.f, 0.f};

    #pragma unroll
    for (int ks = 0; ks < 2; ++ks) {
        bf16x8 a[4];
        #pragma unroll
        for (int m = 0; m < 4; ++m) {
            int mr = m * 16 + cbase;
            a[m] = *(const bf16x8*)((const char*)a_s + mr * 128 + ((ks * 64 + q * 16) ^ ((mr & 7) << 4)));
        }
        #pragma unroll
        for (int n = 0; n < 4; ++n) {
            int bn = wid * 64 + n * 16 + cbase;
            bf16x8 b = *(const bf16x8*)((const char*)w_s + bn * 128 + ((ks * 64 + q * 16) ^ ((bn & 7) << 4)));
            #pragma unroll
            for (int m = 0; m < 4; ++m)
                acc[m][n] = __builtin_amdgcn_mfma_f32_16x16x32_bf16(a[m], b, acc[m][n], 0, 0, 0);
        }
    }

    #pragma unroll
    for (int n = 0; n < 4; ++n) {
        int col = wid * 64 + n * 16 + cbase;
        unsigned short* outp;
        int oidx;
        float bias = 0.f;
        if (col < 64)       { outp = Pd; oidx = 2 * col; }
        else if (col < 128) { outp = Pd; oidx = 2 * (col - 64) + 1; }
        else if (col < 192) { outp = Ps; oidx = 2 * (col - 128);     bias = bfv[col - 128]; }
        else                { outp = Ps; oidx = 2 * (col - 192) + 1; bias = bsv[col - 192]; }
        #pragma unroll
        for (int m = 0; m < 4; ++m) {
            int node = tile * 64 + m * 16 + q * 4;
            #pragma unroll
            for (int r = 0; r < 4; ++r)
                outp[(node + r) * 128 + oidx] = f2b(acc[m][n][r] + bias);
        }
    }
}

// Wave per node. Lane-preloaded edge indices + shfl broadcast; packed F/S dword
// loads; 4-deep unroll. LAYER 1: h1b = bf16(x+agg). LAYER 2: fused readout.
template <int LAYER>
__global__ __launch_bounds__(256) void k_gather(const unsigned int* __restrict__ Pd,
                                                const unsigned int* __restrict__ Ps,
                                                const int* __restrict__ esrc, const int* __restrict__ start,
                                                const int* __restrict__ deg, const float* __restrict__ x,
                                                unsigned short* __restrict__ h1b,
                                                const float* __restrict__ surf, const float* __restrict__ Wlin,
                                                float* __restrict__ scal) {
    const int lane = threadIdx.x & 63, wid = threadIdx.x >> 6;
    const int gw = blockIdx.x * 4 + wid, nw = gridDim.x * 4;
    float wlin = (LAYER == 2) ? Wlin[lane] : 0.f;
    float so = 0.f, ssum = 0.f;

    for (int n = gw; n < NN; n += nw) {
        unsigned int dv = Pd[n * 64 + lane];
        float fd = lo16f(dv), sd = hi16f(dv);
        int b = start[n], d = deg[n];
        int pre = (d < 64) ? d : 64;
        int idx = (lane < pre) ? esrc[b + lane] : 0;
        float a0 = 0.f, a1 = 0.f, a2 = 0.f, a3 = 0.f;
        int j = 0;
        for (; j + 3 < pre; j += 4) {
            int s0 = __shfl(idx, j);
            int s1 = __shfl(idx, j + 1);
            int s2 = __shfl(idx, j + 2);
            int s3 = __shfl(idx, j + 3);
            unsigned int v0 = Ps[s0 * 64 + lane];
            unsigned int v1 = Ps[s1 * 64 + lane];
            unsigned int v2 = Ps[s2 * 64 + lane];
            unsigned int v3 = Ps[s3 * 64 + lane];
            a0 += sigsp(fd + lo16f(v0), sd + hi16f(v0));
            a1 += sigsp(fd + lo16f(v1), sd + hi16f(v1));
            a2 += sigsp(fd + lo16f(v2), sd + hi16f(v2));
            a3 += sigsp(fd + lo16f(v3), sd + hi16f(v3));
        }
        for (; j < d; ++j) {
            int s = (j < 64) ? __shfl(idx, j) : esrc[b + j];
            unsigned int v = Ps[s * 64 + lane];
            a0 += sigsp(fd + lo16f(v), sd + hi16f(v));
        }
        float agg = (a0 + a1) + (a2 + a3);
        if (LAYER == 1) {
            h1b[n * 64 + lane] = f2b(x[n * 64 + lane] + agg);
        } else {
            float v = (b2f(h1b[n * 64 + lane]) + agg) * wlin;
            #pragma unroll
            for (int off = 32; off; off >>= 1) v += __shfl_xor(v, off);
            if (lane == 0) { so += v * surf[n]; ssum += surf[n]; }
        }
    }
    if (LAYER == 2) {
        __shared__ float ps[8];
        if (lane == 0) { ps[wid] = so; ps[4 + wid] = ssum; }
        __syncthreads();
        if (threadIdx.x == 0) {
            atomicAdd(scal + 0, ps[0] + ps[1] + ps[2] + ps[3]);
            atomicAdd(scal + 1, ps[4] + ps[5] + ps[6] + ps[7]);
        }
    }
}

__global__ void k_final(const float* __restrict__ scal, const float* __restrict__ blin,
                        float* __restrict__ out) {
    out[0] = (scal[0] + (float)NN * blin[0]) / scal[1];
}

extern "C" void kernel_launch(void* const* d_in, const int* in_sizes, int n_in,
                              void* d_out, int out_size, void* d_ws, size_t ws_size,
                              hipStream_t stream) {
    const float* x    = (const float*)d_in[0];
    const int*   ei   = (const int*)d_in[1];
    const float* surf = (const float*)d_in[2];
    const float* Wf1  = (const float*)d_in[3];
    const float* bf1  = (const float*)d_in[4];
    const float* Ws1  = (const float*)d_in[5];
    const float* bs1  = (const float*)d_in[6];
    const float* Wf2  = (const float*)d_in[7];
    const float* bf2  = (const float*)d_in[8];
    const float* Ws2  = (const float*)d_in[9];
    const float* bs2  = (const float*)d_in[10];
    const float* Wlin = (const float*)d_in[11];
    const float* blin = (const float*)d_in[12];

    unsigned char* ws = (unsigned char*)d_ws;
    int* deg    = (int*)(ws);                      // 200704 B (N2 ints)
    int* csum   = (int*)(ws + 200704);             // 256 B
    float* scal = (float*)(ws + 200960);           // 64 B
    int* start  = (int*)(ws + 201024);             // 200704 B
    int* cursor = (int*)(ws + 401728);             // 200704 B
    int* esrc   = (int*)(ws + 602432);             // 3,200,000 B
    unsigned short* h1b = (unsigned short*)(ws + 3802432);   // 6,406,144 B
    unsigned short* Pd  = (unsigned short*)(ws + 10208576);  // 12,812,288 B
    unsigned short* Ps  = (unsigned short*)(ws + 23020864);  // 12,812,288 B
    unsigned short* wt  = (unsigned short*)(ws + 35833152);  // 65,536 B

    hipMemsetAsync(d_ws, 0, 201024, stream);  // deg + csum + scal

    k_prep_w<<<128, 256, 0, stream>>>(Wf1, Ws1, Wf2, Ws2, wt);
    k_deg<<<3125, 256, 0, stream>>>(ei, deg);
    k_scan1<<<49, 1024, 0, stream>>>(deg, start, csum);
    k_scan2<<<1, 64, 0, stream>>>(csum);
    k_scan3<<<49, 1024, 0, stream>>>(start, csum, cursor);
    k_fill<<<3125, 256, 0, stream>>>(ei, cursor, esrc);

    k_proj<true><<<NTILE, 256, 0, stream>>>(x, wt, bf1, bs1, Pd, Ps);
    k_gather<1><<<2048, 256, 0, stream>>>((const unsigned int*)Pd, (const unsigned int*)Ps,
                                          esrc, start, deg, x, h1b, surf, Wlin, scal);
    k_proj<false><<<NTILE, 256, 0, stream>>>(h1b, wt + 16384, bf2, bs2, Pd, Ps);
    k_gather<2><<<2048, 256, 0, stream>>>((const unsigned int*)Pd, (const unsigned int*)Ps,
                                          esrc, start, deg, x, h1b, surf, Wlin, scal);
    k_final<<<1, 1, 0, stream>>>(scal, blin, (float*)d_out);
}

// Round 4
// 264.519 us; speedup vs baseline: 1.7290x; 1.1438x over previous
//
#include <hip/hip_runtime.h>

// CGConv x2 + masked readout. N=50000, E=800000, C=64.
// Per-node projections (MFMA) + CSR gather.
// R4: wave-uniform scalar index chain in gather, edge-balanced wave partition
// (binary search over start[]), pre-scaled P tables (exp2/log2 math, ln2 fold),
// merged prep/scan launches.
//
// ws layout: deg(200704) csum(256) scal(64) start(200704) cursor(200704)
// esrc(3.2M) h1b(6.4M) Pd(12.8M) Ps(12.8M) wt(64K)

#define NN 50000
#define EE 800000
#define N2 50176          // 49*1024, padded for scan
#define NTILE 782         // ceil(50000/64)
#define NWAVES 8192
#define EPW 98            // ceil(EE/NWAVES)

typedef short bf16x8 __attribute__((ext_vector_type(8)));
typedef float f32x4 __attribute__((ext_vector_type(4)));
typedef unsigned int uint4v __attribute__((ext_vector_type(4)));
typedef unsigned short u16x4 __attribute__((ext_vector_type(4)));

#define LN2F 0.6931471805599453f
#define L2EF 1.4426950408889634f

#if __has_builtin(__builtin_amdgcn_exp2f)
#define EXP2(x) __builtin_amdgcn_exp2f(x)
#else
#define EXP2(x) __expf(LN2F * (x))
#endif
#if __has_builtin(__builtin_amdgcn_logf)
#define LOG2(x) __builtin_amdgcn_logf(x)
#else
#define LOG2(x) (L2EF * __logf(x))
#endif
#if __has_builtin(__builtin_amdgcn_rcpf)
#define RCPF(x) __builtin_amdgcn_rcpf(x)
#else
#define RCPF(x) (1.0f / (x))
#endif

__device__ __forceinline__ unsigned short f2b(float f) {
    unsigned int u = __builtin_bit_cast(unsigned int, f);
    return (unsigned short)((u + 0x7fffu + ((u >> 16) & 1u)) >> 16);
}
__device__ __forceinline__ float b2f(unsigned short b) {
    unsigned int u = ((unsigned int)b) << 16;
    return __builtin_bit_cast(float, u);
}
__device__ __forceinline__ float lo16f(unsigned int v) {
    return __builtin_bit_cast(float, v << 16);
}
__device__ __forceinline__ float hi16f(unsigned int v) {
    return __builtin_bit_cast(float, v & 0xFFFF0000u);
}
// per-edge message / ln2, with pre-scaled inputs: nF = -log2e*F, Sp = log2e*S
__device__ __forceinline__ float msg2(float nF, float Sp) {
    return RCPF(1.f + EXP2(nF)) * LOG2(1.f + EXP2(Sp));
}

// deg count + (blocks 0..127) weight prep.
// wt[layer][n][k] bf16, n=out col 0..255 ([Wf_top|Ws_top|Wf_bot|Ws_bot]),
// k=in chan 0..63, pre-XOR-swizzled for linear LDS copy.
__global__ __launch_bounds__(256) void k_deg_prep(const int* __restrict__ ei, int* __restrict__ deg,
                                                  const float* __restrict__ Wf1, const float* __restrict__ Ws1,
                                                  const float* __restrict__ Wf2, const float* __restrict__ Ws2,
                                                  unsigned short* __restrict__ wt) {
    int e = blockIdx.x * 256 + threadIdx.x;
    if (blockIdx.x < 128) {
        int i = e;               // 0..32767
        int layer = i >> 14;
        int j = i & 16383;
        int n = j >> 6, k = j & 63;
        const float* Wf = layer ? Wf2 : Wf1;
        const float* Ws = layer ? Ws2 : Ws1;
        float v;
        if (n < 64)       v = Wf[k * 64 + n];
        else if (n < 128) v = Ws[k * 64 + (n - 64)];
        else if (n < 192) v = Wf[(64 + k) * 64 + (n - 128)];
        else              v = Ws[(64 + k) * 64 + (n - 192)];
        int byte = ((n * 128 + k * 2) ^ ((n & 7) << 4)) + layer * 32768;
        *(unsigned short*)((char*)wt + byte) = f2b(v);
    }
    atomicAdd(&deg[ei[EE + e]], 1);
}

__global__ __launch_bounds__(1024) void k_scan1(const int* __restrict__ deg, int* __restrict__ start,
                                                int* __restrict__ csum) {
    __shared__ int s[1024];
    int t = threadIdx.x;
    int i = blockIdx.x * 1024 + t;
    int v = deg[i];
    s[t] = v; __syncthreads();
    for (int off = 1; off < 1024; off <<= 1) {
        int y = (t >= off) ? s[t - off] : 0; __syncthreads();
        s[t] += y; __syncthreads();
    }
    start[i] = s[t] - v;
    if (t == 1023) csum[blockIdx.x] = s[t];
}

// cross-block offset (reduce csum[0..blockIdx)) + apply, + init cursor
__global__ __launch_bounds__(1024) void k_scan23(int* __restrict__ start, const int* __restrict__ csum,
                                                 int* __restrict__ cursor) {
    __shared__ int red[1024];
    int t = threadIdx.x;
    red[t] = (t < (int)blockIdx.x) ? csum[t] : 0;
    __syncthreads();
    for (int off = 512; off; off >>= 1) {
        if (t < off) red[t] += red[t + off];
        __syncthreads();
    }
    int base = red[0];
    int i = blockIdx.x * 1024 + t;
    int nv = start[i] + base;
    start[i] = nv;
    cursor[i] = nv;
}

__global__ __launch_bounds__(256) void k_fill(const int* __restrict__ ei, int* __restrict__ cursor,
                                              int* __restrict__ esrc) {
    int e = blockIdx.x * 256 + threadIdx.x;
    int dst = ei[EE + e];
    int p = atomicAdd(&cursor[dst], 1);
    esrc[p] = ei[e];
}

// P = H @ Wcat, 64 nodes x 256 cols per block, 4 waves.
// Output (per node, 64 dwords): dword c = [ -log2e*F_c (lo16) | log2e*S_c (hi16) ].
// Pd: no bias. Ps: +bf/+bs folded in before scaling.
template <bool F32IN>
__global__ __launch_bounds__(256) void k_proj(const void* __restrict__ hin,
                                              const unsigned short* __restrict__ wt,
                                              const float* __restrict__ bfv, const float* __restrict__ bsv,
                                              unsigned short* __restrict__ Pd, unsigned short* __restrict__ Ps) {
    __shared__ unsigned short w_s[256 * 64];  // 32KB swizzled
    __shared__ unsigned short a_s[64 * 64];   // 8KB swizzled
    const int t = threadIdx.x;
    {
        const uint4v* src = (const uint4v*)wt;
        uint4v* dp = (uint4v*)w_s;
        #pragma unroll
        for (int i = 0; i < 8; ++i) dp[t + 256 * i] = src[t + 256 * i];
    }
    const int lane = t & 63, wid = t >> 6;
    const int cbase = lane & 15, q = lane >> 4;
    const int tile = blockIdx.x;

    #pragma unroll
    for (int i = 0; i < 2; ++i) {
        int ch = t + 256 * i;
        int r = ch >> 3, c8 = ch & 7;
        int node = tile * 64 + r;
        u16x4 lo = {0, 0, 0, 0}, hi = {0, 0, 0, 0};
        if (node < NN) {
            if (F32IN) {
                const float* xp = (const float*)hin + node * 64 + c8 * 8;
                f32x4 v0 = *(const f32x4*)xp;
                f32x4 v1 = *(const f32x4*)(xp + 4);
                lo[0] = f2b(v0[0]); lo[1] = f2b(v0[1]); lo[2] = f2b(v0[2]); lo[3] = f2b(v0[3]);
                hi[0] = f2b(v1[0]); hi[1] = f2b(v1[1]); hi[2] = f2b(v1[2]); hi[3] = f2b(v1[3]);
            } else {
                const unsigned short* hp = (const unsigned short*)hin + node * 64 + c8 * 8;
                lo = *(const u16x4*)hp;
                hi = *(const u16x4*)(hp + 4);
            }
        }
        int byte = (r * 128 + c8 * 16) ^ ((r & 7) << 4);
        *(u16x4*)((char*)a_s + byte) = lo;
        *(u16x4*)((char*)a_s + byte + 8) = hi;
    }
    __syncthreads();

    f32x4 acc[4][4];
    #pragma unroll
    for (int m = 0; m < 4; ++m)
        #pragma unroll
        for (int n = 0; n < 4; ++n) acc[m][n] = (f32x4){0.f, 0.f, 0.f, 0.f};

    #pragma unroll
    for (int ks = 0; ks < 2; ++ks) {
        bf16x8 a[4];
        #pragma unroll
        for (int m = 0; m < 4; ++m) {
            int mr = m * 16 + cbase;
            a[m] = *(const bf16x8*)((const char*)a_s + mr * 128 + ((ks * 64 + q * 16) ^ ((mr & 7) << 4)));
        }
        #pragma unroll
        for (int n = 0; n < 4; ++n) {
            int bn = wid * 64 + n * 16 + cbase;
            bf16x8 b = *(const bf16x8*)((const char*)w_s + bn * 128 + ((ks * 64 + q * 16) ^ ((bn & 7) << 4)));
            #pragma unroll
            for (int m = 0; m < 4; ++m)
                acc[m][n] = __builtin_amdgcn_mfma_f32_16x16x32_bf16(a[m], b, acc[m][n], 0, 0, 0);
        }
    }

    #pragma unroll
    for (int n = 0; n < 4; ++n) {
        int col = wid * 64 + n * 16 + cbase;
        unsigned short* outp;
        int oidx;
        float bias = 0.f, scale;
        if (col < 64)       { outp = Pd; oidx = 2 * col;             scale = -L2EF; }
        else if (col < 128) { outp = Pd; oidx = 2 * (col - 64) + 1;  scale =  L2EF; }
        else if (col < 192) { outp = Ps; oidx = 2 * (col - 128);     scale = -L2EF; bias = bfv[col - 128]; }
        else                { outp = Ps; oidx = 2 * (col - 192) + 1; scale =  L2EF; bias = bsv[col - 192]; }
        #pragma unroll
        for (int m = 0; m < 4; ++m) {
            int node = tile * 64 + m * 16 + q * 4;
            #pragma unroll
            for (int r = 0; r < 4; ++r)
                outp[(node + r) * 128 + oidx] = f2b((acc[m][n][r] + bias) * scale);
        }
    }
}

// Edge-balanced wave-per-node-range gather. Wave w owns nodes with
// floor(start[n]/EPW)==w (binary search). Whole index chain wave-uniform ->
// scalar loads; Ps row loads are the only vector memory ops.
template <int LAYER>
__global__ __launch_bounds__(256) void k_gather(const unsigned int* __restrict__ Pd,
                                                const unsigned int* __restrict__ Ps,
                                                const int* __restrict__ esrc, const int* __restrict__ start,
                                                const float* __restrict__ x,
                                                unsigned short* __restrict__ h1b,
                                                const float* __restrict__ surf, const float* __restrict__ Wlin,
                                                float* __restrict__ scal) {
    const int lane = threadIdx.x & 63;
    const int wid = __builtin_amdgcn_readfirstlane(threadIdx.x >> 6);
    const int w = blockIdx.x * 4 + wid;

    int t0 = w * EPW, t1 = t0 + EPW;
    int lo = 0, hi = NN;
    while (lo < hi) { int mid = (lo + hi) >> 1; if (start[mid] < t0) lo = mid + 1; else hi = mid; }
    const int n0 = lo;
    hi = NN;
    while (lo < hi) { int mid = (lo + hi) >> 1; if (start[mid] < t1) lo = mid + 1; else hi = mid; }
    const int n1 = lo;

    float wlin = (LAYER == 2) ? Wlin[lane] : 0.f;
    float so = 0.f, ssum = 0.f;

    for (int n = n0; n < n1; ++n) {
        int b = __builtin_amdgcn_readfirstlane(start[n]);
        int d = __builtin_amdgcn_readfirstlane(start[n + 1]) - b;
        unsigned int dv = Pd[n * 64 + lane];
        float nfd = lo16f(dv), sd = hi16f(dv);
        float a0 = 0.f, a1 = 0.f, a2 = 0.f, a3 = 0.f;
        int j = 0;
        for (; j + 3 < d; j += 4) {
            int s0 = __builtin_amdgcn_readfirstlane(esrc[b + j]);
            int s1 = __builtin_amdgcn_readfirstlane(esrc[b + j + 1]);
            int s2 = __builtin_amdgcn_readfirstlane(esrc[b + j + 2]);
            int s3 = __builtin_amdgcn_readfirstlane(esrc[b + j + 3]);
            unsigned int v0 = Ps[s0 * 64 + lane];
            unsigned int v1 = Ps[s1 * 64 + lane];
            unsigned int v2 = Ps[s2 * 64 + lane];
            unsigned int v3 = Ps[s3 * 64 + lane];
            a0 += msg2(nfd + lo16f(v0), sd + hi16f(v0));
            a1 += msg2(nfd + lo16f(v1), sd + hi16f(v1));
            a2 += msg2(nfd + lo16f(v2), sd + hi16f(v2));
            a3 += msg2(nfd + lo16f(v3), sd + hi16f(v3));
        }
        for (; j < d; ++j) {
            int s = __builtin_amdgcn_readfirstlane(esrc[b + j]);
            unsigned int v = Ps[s * 64 + lane];
            a0 += msg2(nfd + lo16f(v), sd + hi16f(v));
        }
        float agg = LN2F * ((a0 + a1) + (a2 + a3));
        if (LAYER == 1) {
            h1b[n * 64 + lane] = f2b(x[n * 64 + lane] + agg);
        } else {
            float v = (b2f(h1b[n * 64 + lane]) + agg) * wlin;
            #pragma unroll
            for (int off = 32; off; off >>= 1) v += __shfl_xor(v, off);
            if (lane == 0) { so += v * surf[n]; ssum += surf[n]; }
        }
    }
    if (LAYER == 2) {
        __shared__ float ps[8];
        if (lane == 0) { ps[wid] = so; ps[4 + wid] = ssum; }
        __syncthreads();
        if (threadIdx.x == 0) {
            atomicAdd(scal + 0, ps[0] + ps[1] + ps[2] + ps[3]);
            atomicAdd(scal + 1, ps[4] + ps[5] + ps[6] + ps[7]);
        }
    }
}

__global__ void k_final(const float* __restrict__ scal, const float* __restrict__ blin,
                        float* __restrict__ out) {
    out[0] = (scal[0] + (float)NN * blin[0]) / scal[1];
}

extern "C" void kernel_launch(void* const* d_in, const int* in_sizes, int n_in,
                              void* d_out, int out_size, void* d_ws, size_t ws_size,
                              hipStream_t stream) {
    const float* x    = (const float*)d_in[0];
    const int*   ei   = (const int*)d_in[1];
    const float* surf = (const float*)d_in[2];
    const float* Wf1  = (const float*)d_in[3];
    const float* bf1  = (const float*)d_in[4];
    const float* Ws1  = (const float*)d_in[5];
    const float* bs1  = (const float*)d_in[6];
    const float* Wf2  = (const float*)d_in[7];
    const float* bf2  = (const float*)d_in[8];
    const float* Ws2  = (const float*)d_in[9];
    const float* bs2  = (const float*)d_in[10];
    const float* Wlin = (const float*)d_in[11];
    const float* blin = (const float*)d_in[12];

    unsigned char* ws = (unsigned char*)d_ws;
    int* deg    = (int*)(ws);                      // 200704 B (N2 ints)
    int* csum   = (int*)(ws + 200704);             // 256 B
    float* scal = (float*)(ws + 200960);           // 64 B
    int* start  = (int*)(ws + 201024);             // 200704 B
    int* cursor = (int*)(ws + 401728);             // 200704 B
    int* esrc   = (int*)(ws + 602432);             // 3,200,000 B
    unsigned short* h1b = (unsigned short*)(ws + 3802432);   // 6,406,144 B
    unsigned short* Pd  = (unsigned short*)(ws + 10208576);  // 12,812,288 B
    unsigned short* Ps  = (unsigned short*)(ws + 23020864);  // 12,812,288 B
    unsigned short* wt  = (unsigned short*)(ws + 35833152);  // 65,536 B

    hipMemsetAsync(d_ws, 0, 201024, stream);  // deg + csum + scal

    k_deg_prep<<<3125, 256, 0, stream>>>(ei, deg, Wf1, Ws1, Wf2, Ws2, wt);
    k_scan1<<<49, 1024, 0, stream>>>(deg, start, csum);
    k_scan23<<<49, 1024, 0, stream>>>(start, csum, cursor);
    k_fill<<<3125, 256, 0, stream>>>(ei, cursor, esrc);

    k_proj<true><<<NTILE, 256, 0, stream>>>(x, wt, bf1, bs1, Pd, Ps);
    k_gather<1><<<2048, 256, 0, stream>>>((const unsigned int*)Pd, (const unsigned int*)Ps,
                                          esrc, start, x, h1b, surf, Wlin, scal);
    k_proj<false><<<NTILE, 256, 0, stream>>>(h1b, wt + 16384, bf2, bs2, Pd, Ps);
    k_gather<2><<<2048, 256, 0, stream>>>((const unsigned int*)Pd, (const unsigned int*)Ps,
                                          esrc, start, x, h1b, surf, Wlin, scal);
    k_final<<<1, 1, 0, stream>>>(scal, blin, (float*)d_out);
}